// Round 1
// baseline (1003.374 us; speedup 1.0000x reference)
//
#include <hip/hip_runtime.h>

#define F_IN 128
#define HID 64
#define NCLS 40

// ---------------- degree ----------------
__global__ void deg_kernel(const int* __restrict__ dst, float* __restrict__ deg, int E) {
    int i = blockIdx.x * blockDim.x + threadIdx.x;
    if (i < E) atomicAdd(&deg[dst[i]], 1.0f);
}

// ---------------- layer-1 fused GEMM: p1 = x@W1l, q1 = x@W1r + b1 ----------------
__global__ __launch_bounds__(256) void gemm1_kernel(
    const float* __restrict__ x, const float* __restrict__ Wl,
    const float* __restrict__ Wr, const float* __restrict__ b1,
    float* __restrict__ p1, float* __restrict__ q1, int N)
{
    __shared__ float sWl[F_IN * HID];   // 32 KB
    __shared__ float sWr[F_IN * HID];   // 32 KB
    __shared__ float sx[16 * F_IN];     // 8 KB
    const int tid = threadIdx.x;
    for (int idx = tid; idx < F_IN * HID; idx += 256) {
        sWl[idx] = Wl[idx];
        sWr[idx] = Wr[idx];
    }
    const int node0 = blockIdx.x * 16;
    for (int idx = tid; idx < 16 * F_IN; idx += 256) {
        int n = node0 + (idx >> 7);
        sx[idx] = (n < N) ? x[(size_t)node0 * F_IN + idx] : 0.0f;
    }
    __syncthreads();
    const int f = tid & 63;
    const int r0 = tid >> 6;   // 0..3
    float accL[4] = {0.f, 0.f, 0.f, 0.f};
    float accR[4] = {0.f, 0.f, 0.f, 0.f};
    #pragma unroll 8
    for (int k = 0; k < F_IN; k++) {
        float wl = sWl[k * HID + f];
        float wr = sWr[k * HID + f];
        #pragma unroll
        for (int i = 0; i < 4; i++) {
            float xv = sx[(r0 + i * 4) * F_IN + k];
            accL[i] += xv * wl;
            accR[i] += xv * wr;
        }
    }
    const float bb = b1[f];
    #pragma unroll
    for (int i = 0; i < 4; i++) {
        int n = node0 + r0 + i * 4;
        if (n < N) {
            p1[n * HID + f] = accL[i];
            q1[n * HID + f] = accR[i] + bb;
        }
    }
}

// ---------------- scatter-add layer 1: agg1[dst] += p1[src], 64 feats ----------------
__global__ __launch_bounds__(256) void scatter1_kernel(
    const int* __restrict__ src, const int* __restrict__ dst,
    const float* __restrict__ p1, float* __restrict__ agg, int E)
{
    int i = blockIdx.x * 256 + threadIdx.x;
    int e = i >> 6;
    int f = i & 63;
    if (e < E) {
        int s = src[e];
        int d = dst[e];
        atomicAdd(&agg[d * HID + f], p1[s * HID + f]);
    }
}

// ---------------- h = relu(agg1/deg + q1) ----------------
__global__ __launch_bounds__(256) void h_kernel(
    float* __restrict__ q1, const float* __restrict__ agg,
    const float* __restrict__ deg, int N)
{
    int i = blockIdx.x * 256 + threadIdx.x;
    if (i < N * HID) {
        int n = i >> 6;
        float dg = deg[n];
        dg = dg > 1.f ? dg : 1.f;
        float v = agg[i] / dg + q1[i];
        q1[i] = v > 0.f ? v : 0.f;
    }
}

// ---------------- layer-2 GEMM: p2 = h@W2l ----------------
__global__ __launch_bounds__(320) void gemm2_kernel(
    const float* __restrict__ h, const float* __restrict__ W2l,
    float* __restrict__ p2, int N)
{
    __shared__ float sW[HID * NCLS];  // 10 KB
    __shared__ float sh[8 * HID];     // 2 KB
    const int tid = threadIdx.x;
    for (int idx = tid; idx < HID * NCLS; idx += 320) sW[idx] = W2l[idx];
    const int node0 = blockIdx.x * 8;
    for (int idx = tid; idx < 8 * HID; idx += 320) {
        int n = node0 + (idx >> 6);
        sh[idx] = (n < N) ? h[(size_t)node0 * HID + idx] : 0.f;
    }
    __syncthreads();
    const int j = tid % NCLS;
    const int r = tid / NCLS;
    float acc = 0.f;
    #pragma unroll
    for (int k = 0; k < HID; k++) acc += sh[r * HID + k] * sW[k * NCLS + j];
    int n = node0 + r;
    if (n < N) p2[n * NCLS + j] = acc;
}

// ---------------- scatter-add layer 2: agg2[dst] += p2[src], 40 feats ----------------
__global__ __launch_bounds__(320) void scatter2_kernel(
    const int* __restrict__ src, const int* __restrict__ dst,
    const float* __restrict__ p2, float* __restrict__ agg, int E)
{
    int tid = threadIdx.x;
    int e = blockIdx.x * 8 + tid / NCLS;
    int f = tid % NCLS;
    if (e < E) {
        int s = src[e];
        int d = dst[e];
        atomicAdd(&agg[d * NCLS + f], p2[s * NCLS + f]);
    }
}

// ---------------- final: o = agg2/deg + h@W2r + b2; out = log_softmax(o) ----------------
__global__ __launch_bounds__(320) void final_kernel(
    const float* __restrict__ h, const float* __restrict__ W2r,
    const float* __restrict__ b2, const float* __restrict__ agg2,
    const float* __restrict__ deg, float* __restrict__ out, int N)
{
    __shared__ float sW[HID * NCLS];  // 10 KB
    __shared__ float sh[8 * HID];     // 2 KB
    __shared__ float so[320];
    const int tid = threadIdx.x;
    for (int idx = tid; idx < HID * NCLS; idx += 320) sW[idx] = W2r[idx];
    const int node0 = blockIdx.x * 8;
    for (int idx = tid; idx < 8 * HID; idx += 320) {
        int n = node0 + (idx >> 6);
        sh[idx] = (n < N) ? h[(size_t)node0 * HID + idx] : 0.f;
    }
    __syncthreads();
    const int j = tid % NCLS;
    const int r = tid / NCLS;
    const int n = node0 + r;
    float acc = 0.f;
    #pragma unroll
    for (int k = 0; k < HID; k++) acc += sh[r * HID + k] * sW[k * NCLS + j];
    float dg = (n < N) ? deg[n] : 1.f;
    dg = dg > 1.f ? dg : 1.f;
    float o = acc + b2[j] + ((n < N) ? agg2[n * NCLS + j] : 0.f) / dg;
    so[tid] = o;
    __syncthreads();
    float m = -1e30f;
    #pragma unroll
    for (int k = 0; k < NCLS; k++) m = fmaxf(m, so[r * NCLS + k]);
    float s = 0.f;
    #pragma unroll
    for (int k = 0; k < NCLS; k++) s += __expf(so[r * NCLS + k] - m);
    if (n < N) out[n * NCLS + j] = o - m - __logf(s);
}

extern "C" void kernel_launch(void* const* d_in, const int* in_sizes, int n_in,
                              void* d_out, int out_size, void* d_ws, size_t ws_size,
                              hipStream_t stream) {
    const float* x   = (const float*)d_in[0];
    const int*   ei  = (const int*)d_in[1];
    const float* W1l = (const float*)d_in[2];
    const float* W1r = (const float*)d_in[3];
    const float* b1  = (const float*)d_in[4];
    const float* W2l = (const float*)d_in[5];
    const float* W2r = (const float*)d_in[6];
    const float* b2  = (const float*)d_in[7];

    const int N = in_sizes[0] / F_IN;
    const int E = in_sizes[1] / 2;
    const int* src = ei;
    const int* dst = ei + E;

    float* ws   = (float*)d_ws;
    float* deg  = ws;                         // N
    float* agg  = ws + N;                     // 64N (agg1; reused as agg2 40N)
    float* hbuf = ws + N + 64LL * N;          // 64N (q1 -> h)
    float* p1   = ws + N + 128LL * N;         // 64N (p1; reused as p2 40N)
    float* out  = (float*)d_out;

    // zero deg + agg1 (contiguous)
    hipMemsetAsync(deg, 0, (size_t)(N + 64LL * N) * sizeof(float), stream);

    deg_kernel<<<(E + 255) / 256, 256, 0, stream>>>(dst, deg, E);
    gemm1_kernel<<<(N + 15) / 16, 256, 0, stream>>>(x, W1l, W1r, b1, p1, hbuf, N);
    {
        long long tot = (long long)E * 64;
        scatter1_kernel<<<(int)((tot + 255) / 256), 256, 0, stream>>>(src, dst, p1, agg, E);
    }
    {
        long long tot = (long long)N * HID;
        h_kernel<<<(int)((tot + 255) / 256), 256, 0, stream>>>(hbuf, agg, deg, N);
    }
    // zero agg2 (reuses agg1 region)
    hipMemsetAsync(agg, 0, (size_t)40LL * N * sizeof(float), stream);

    gemm2_kernel<<<(N + 7) / 8, 320, 0, stream>>>(hbuf, W2l, p1, N);
    scatter2_kernel<<<(E + 7) / 8, 320, 0, stream>>>(src, dst, p1, agg, E);
    final_kernel<<<(N + 7) / 8, 320, 0, stream>>>(hbuf, W2r, b2, agg, deg, out, N);
}